// Round 9
// baseline (1459.629 us; speedup 1.0000x reference)
//
#include <hip/hip_runtime.h>

typedef __attribute__((ext_vector_type(8))) _Float16 f16x8;
typedef __attribute__((ext_vector_type(4))) float    f32x4;

#define HD    256
#define CIN   16
#define TIN   48
#define TOUT  24
#define COUT  8
#define MB    32            // batch rows per block
#define KPAD  296           // padded row stride (halves) for hF
#define KT_ENC 9            // K = 288 (h 256 | x 16 | pad 16)
#define KT_DEC 8            // K = 256
#define WE_HALVES (KT_ENC*4*16*512)   // 294912
#define WD_HALVES (KT_DEC*4*16*512)   // 262144
#define PREP_TOTAL (WE_HALVES + WD_HALVES)
#define NREP  8             // one weight-buffer copy per XCD (kept from r8, harmless)

template <int N> struct KTag { static constexpr int val = N; };

// Fragment-major fp16 weights: frag id = kt*64 + g*16 + ntile, each frag is
// 64 lanes x 8 halves with b_frag[lane][s] = W[k = kt*32 + (lane>>4)*8 + s]
//                                             [col = g*256 + ntile*16 + (lane&15)]
__global__ void prep_frags(const float* __restrict__ enc_Wih,
                           const float* __restrict__ enc_Whh,
                           const float* __restrict__ dec_Whh,
                           _Float16* __restrict__ wf)
{
    int p = blockIdx.x * blockDim.x + threadIdx.x;
    if (p >= PREP_TOTAL) return;
    int lane = (p >> 3) & 63;
    int s    = p & 7;
    int kq   = ((lane >> 4) << 3) + s;
    int l15  = lane & 15;
    float v;
    if (p < WE_HALVES) {
        int frag = p >> 9;
        int kt = frag >> 6, g = (frag >> 4) & 3, ntile = frag & 15;
        int k   = kt * 32 + kq;
        int row = g * 256 + ntile * 16 + l15;
        v = 0.0f;
        if (k < 256)      v = enc_Whh[row * 256 + k];
        else if (k < 272) v = enc_Wih[row * 16 + (k - 256)];
    } else {
        int q = p - WE_HALVES;
        int frag = q >> 9;
        int kt = frag >> 6, g = (frag >> 4) & 3, ntile = frag & 15;
        int k   = kt * 32 + kq;
        int row = g * 256 + ntile * 16 + l15;
        v = dec_Whh[row * 256 + k];
    }
    _Float16 hv = (_Float16)v;
    #pragma unroll
    for (int rep = 0; rep < NREP; ++rep)
        wf[(size_t)rep * PREP_TOTAL + p] = hv;
}

__device__ __forceinline__ float sigm(float v) {
    return __builtin_amdgcn_rcpf(1.0f + __expf(-v));
}
__device__ __forceinline__ float tanh_f(float v) {
    return 1.0f - 2.0f * __builtin_amdgcn_rcpf(1.0f + __expf(2.0f * v));
}

// grid = 256 blocks (1/CU), 512 threads = 8 waves (2/SIMD -> 256 VGPR/wave).
// Wave w owns ntiles {2w, 2w+1} for all 4 gates, both 16-row M-tiles.
// Weight-stream MLP is forced in source: chunk-0 (8 frags) persists in regs
// per phase; chunks 1..KT-1 flow through a 2-buffer register ping-pong whose
// WAR hazards keep ~2 chunks (16 loads) in flight per wave at all times.
__global__ __launch_bounds__(512, 2) void seq2seq_mfma(
    const float* __restrict__ x,
    const _Float16* __restrict__ wf,
    const float* __restrict__ enc_b,
    const float* __restrict__ dec_b,
    const float* __restrict__ denseW,
    const float* __restrict__ denseb,
    float* __restrict__ out)
{
    __shared__ __align__(16) _Float16 hF[MB * KPAD];          // 18.5 KB
    __shared__ __align__(16) _Float16 xs[2][MB * CIN * 8];    // 16 KB
    __shared__ __align__(16) float    outS[MB * COUT * TOUT]; // 24 KB

    const int tid  = threadIdx.x;
    const int w    = tid >> 6;
    const int lane = tid & 63;
    const int quad = lane >> 4;
    const int l15  = lane & 15;
    const int n0   = blockIdx.x * MB;

    const _Float16* wfb = wf + (size_t)(blockIdx.x & 7) * PREP_TOTAL;

    float bE[4][2], bD[4][2];
    #pragma unroll
    for (int g = 0; g < 4; ++g)
        #pragma unroll
        for (int nt = 0; nt < 2; ++nt) {
            int col = (w * 2 + nt) * 16 + l15;
            bE[g][nt] = enc_b[g * 256 + col];
            bD[g][nt] = dec_b[g * 256 + col];
        }

    auto loadchunk = [&](int wd) {   // stage x[:, :, wd*8 .. wd*8+8) -> xs[wd&1]
        int m = tid >> 4, c = tid & 15;
        const float* xp = x + (size_t)(n0 + m) * (CIN * TIN) + c * TIN + wd * 8;
        float4 v0 = *(const float4*)xp;
        float4 v1 = *(const float4*)(xp + 4);
        f16x8 hv = { (_Float16)v0.x, (_Float16)v0.y, (_Float16)v0.z, (_Float16)v0.w,
                     (_Float16)v1.x, (_Float16)v1.y, (_Float16)v1.z, (_Float16)v1.w };
        *(f16x8*)(&xs[wd & 1][m * (CIN * 8) + c * 8]) = hv;
    };
    auto xcopy = [&](int t) {        // xs -> hF x-slot for step t
        int m = tid >> 4, c = tid & 15;
        hF[m * KPAD + 256 + c] = xs[(t >> 3) & 1][m * (CIN * 8) + c * 8 + (t & 7)];
    };

    for (int i = tid; i < MB * KPAD; i += 512) hF[i] = (_Float16)0.0f;
    loadchunk(0);
    __syncthreads();
    xcopy(0);
    __syncthreads();

    f32x4 acc[2][4][2];        // [Mtile][gate][nt]
    float cst[2][2][4];        // c-state, C-frag layout
    #pragma unroll
    for (int mt = 0; mt < 2; ++mt)
        #pragma unroll
        for (int nt = 0; nt < 2; ++nt)
            #pragma unroll
            for (int r = 0; r < 4; ++r) cst[mt][nt][r] = 0.0f;

    const f16x8* Ap0 = (const f16x8*)(hF + l15 * KPAD);          // Mtile 0
    const f16x8* Ap1 = (const f16x8*)(hF + (16 + l15) * KPAD);   // Mtile 1
    const f16x8* WpE = (const f16x8*)wfb + (w * 2) * 64 + lane;
    const f16x8* WpD = (const f16x8*)(wfb + WE_HALVES) + (w * 2) * 64 + lane;

    f16x8 c0[8];        // chunk-0 frags, persist across a phase's t-loop
    f16x8 pf[2][8];     // streaming ping-pong buffers

    auto loadC0 = [&](const f16x8* __restrict__ Wp) {
        #pragma unroll
        for (int g = 0; g < 4; ++g)
            #pragma unroll
            for (int nt = 0; nt < 2; ++nt)
                c0[g * 2 + nt] = Wp[(g * 16 + nt) * 64];
    };
    auto loadPf = [&](f16x8 (&dst)[8], const f16x8* __restrict__ Wp, int kt) {
        #pragma unroll
        for (int g = 0; g < 4; ++g)
            #pragma unroll
            for (int nt = 0; nt < 2; ++nt)
                dst[g * 2 + nt] = Wp[(kt * 64 + g * 16 + nt) * 64];
    };
    auto mfmaChunk = [&](const f16x8 (&wb)[8], int kt) {
        f16x8 a0 = Ap0[kt * 4 + quad];
        f16x8 a1 = Ap1[kt * 4 + quad];
        #pragma unroll
        for (int g = 0; g < 4; ++g)
            #pragma unroll
            for (int nt = 0; nt < 2; ++nt) {
                acc[0][g][nt] = __builtin_amdgcn_mfma_f32_16x16x32_f16(a0, wb[g * 2 + nt], acc[0][g][nt], 0, 0, 0);
                acc[1][g][nt] = __builtin_amdgcn_mfma_f32_16x16x32_f16(a1, wb[g * 2 + nt], acc[1][g][nt], 0, 0, 0);
            }
    };

    auto gemm = [&](auto kt_tag, const f16x8* __restrict__ Wp, const float (&bias)[4][2]) {
        constexpr int KT = decltype(kt_tag)::val;
        loadPf(pf[1], Wp, 1);            // prefetch chunk 1
        loadPf(pf[0], Wp, 2);            // prefetch chunk 2
        #pragma unroll
        for (int mt = 0; mt < 2; ++mt)
            #pragma unroll
            for (int g = 0; g < 4; ++g)
                #pragma unroll
                for (int nt = 0; nt < 2; ++nt) {
                    float b = bias[g][nt];
                    f32x4 bv = {b, b, b, b};
                    acc[mt][g][nt] = bv;
                }
        mfmaChunk(c0, 0);                // chunk 0 from persistent regs
        #pragma unroll
        for (int kt = 1; kt < KT; ++kt) {
            mfmaChunk(pf[kt & 1], kt);   // consume buffer ...
            if (kt + 2 < KT)
                loadPf(pf[kt & 1], Wp, kt + 2);   // ... then refill 2 ahead
        }
    };

    auto pointwise = [&]() {
        #pragma unroll
        for (int mt = 0; mt < 2; ++mt)
            #pragma unroll
            for (int nt = 0; nt < 2; ++nt) {
                int col = (w * 2 + nt) * 16 + l15;
                #pragma unroll
                for (int r = 0; r < 4; ++r) {
                    float iv = sigm(acc[mt][0][nt][r]);
                    float fv = sigm(acc[mt][1][nt][r]);
                    float gv = tanh_f(acc[mt][2][nt][r]);
                    float ov = sigm(acc[mt][3][nt][r]);
                    float cn = fmaf(fv, cst[mt][nt][r], iv * gv);
                    cst[mt][nt][r] = cn;
                    float hv = ov * tanh_f(cn);
                    hF[(mt * 16 + quad * 4 + r) * KPAD + col] = (_Float16)hv;
                }
            }
    };

    // ================= encoder =================
    loadC0(WpE);
    for (int t = 0; t < TIN; ++t) {
        gemm(KTag<KT_ENC>{}, WpE, bE);
        __syncthreads();              // all A-frag reads done
        pointwise();                  // write h_t
        if ((t & 7) == 0 && (t >> 3) + 1 < 6) loadchunk((t >> 3) + 1);
        if (t + 1 < TIN) xcopy(t + 1);
        __syncthreads();
    }

    // ================= decoder (c resets to 0) =================
    loadC0(WpD);                      // swap persistent chunk-0 to decoder
    #pragma unroll
    for (int mt = 0; mt < 2; ++mt)
        #pragma unroll
        for (int nt = 0; nt < 2; ++nt)
            #pragma unroll
            for (int r = 0; r < 4; ++r) cst[mt][nt][r] = 0.0f;

    for (int t = 0; t < TOUT; ++t) {
        gemm(KTag<KT_DEC>{}, WpD, bD);
        __syncthreads();
        pointwise();
        __syncthreads();
        // dense epilogue -> LDS out buffer (threads 0..255). hF is read-only
        // until the next step's post-gemm barrier -> race-free.
        if (tid < MB * COUT) {
            int m = tid >> 3, o = tid & 7;
            const float* wr = denseW + (t * COUT + o) * HD;
            float s = denseb[t * COUT + o];
            #pragma unroll 4
            for (int j8 = 0; j8 < 32; ++j8) {
                f16x8 hv  = *(const f16x8*)(hF + m * KPAD + j8 * 8);
                float4 w0 = *(const float4*)(wr + j8 * 8);
                float4 w1 = *(const float4*)(wr + j8 * 8 + 4);
                s = fmaf((float)hv[0], w0.x, s);
                s = fmaf((float)hv[1], w0.y, s);
                s = fmaf((float)hv[2], w0.z, s);
                s = fmaf((float)hv[3], w0.w, s);
                s = fmaf((float)hv[4], w1.x, s);
                s = fmaf((float)hv[5], w1.y, s);
                s = fmaf((float)hv[6], w1.z, s);
                s = fmaf((float)hv[7], w1.w, s);
            }
            outS[m * (COUT * TOUT) + o * TOUT + t] = s;
        }
    }

    // ================= coalesced output flush =================
    __syncthreads();
    {
        const float4* src = (const float4*)outS;
        float4* dst = (float4*)(out + (size_t)n0 * (COUT * TOUT));
        #pragma unroll
        for (int i = 0; i < (MB * COUT * TOUT / 4) / 512; ++i)
            dst[tid + i * 512] = src[tid + i * 512];
    }
}

extern "C" void kernel_launch(void* const* d_in, const int* in_sizes, int n_in,
                              void* d_out, int out_size, void* d_ws, size_t ws_size,
                              hipStream_t stream) {
    const float* x       = (const float*)d_in[0];
    const float* enc_Wih = (const float*)d_in[1];
    const float* enc_Whh = (const float*)d_in[2];
    const float* enc_b   = (const float*)d_in[3];
    const float* dec_Whh = (const float*)d_in[4];
    const float* dec_b   = (const float*)d_in[5];
    const float* denseW  = (const float*)d_in[6];
    const float* denseb  = (const float*)d_in[7];
    float* out = (float*)d_out;
    _Float16* wf = (_Float16*)d_ws;   // NREP x 1.09 MB fragment-major fp16 weights

    prep_frags<<<(PREP_TOTAL + 255) / 256, 256, 0, stream>>>(enc_Wih, enc_Whh, dec_Whh, wf);
    seq2seq_mfma<<<8192 / MB, 512, 0, stream>>>(x, wf, enc_b, dec_b, denseW, denseb, out);
}